// Round 5
// baseline (447.269 us; speedup 1.0000x reference)
//
#include <hip/hip_runtime.h>

#define NB 8
#define NPTS 100000
#define C_DIM 32
#define RESO 64
#define R3 (RESO * RESO * RESO)     // 262144 = 2^18
#define CHUNK 1024                  // bins per scan chunk
#define NCHUNK (R3 / CHUNK)         // 256 chunks per batch
#define TOTCHUNK (NB * NCHUNK)      // 2048 chunks total
#define NPTS_TOT (NB * NPTS)        // 800000
#define NTILE ((NPTS + 255) / 256)  // 391 tiles per batch
#define K5_LDS_ROWS 640             // 640 rows * 64 B = 40 KB staging

// Workspace layout (byte offsets, 16B-aligned)
#define OFF_IDX   0u                              // [800000] int
#define OFF_HIST  3200000u                        // [B*R3] int (8 MB)
#define OFF_LSCAN (OFF_HIST + 8388608u)           // [B*R3] int (8 MB)
#define OFF_CTOT  (OFF_LSCAN + 8388608u)          // [2048] int
#define OFF_COFF  (OFF_CTOT + 8192u)              // [2048] int
#define OFF_PERM  (OFF_COFF + 8192u)              // path B: [800000] int
#define OFF_FPERM (OFF_COFF + 8192u)              // path A: [800000][32] fp16 (51.2 MB)
#define WS_NEED_A (OFF_FPERM + (size_t)NPTS_TOT * C_DIM * 2)
#define WS_NEED_B (OFF_PERM + (size_t)NPTS_TOT * 4)

union H8 { uint4 v; _Float16 h[8]; };

// ---------------- K1: bin index per point + histogram ----------------
__global__ void __launch_bounds__(256)
k1_index_hist(const float* __restrict__ points, int* __restrict__ idxArr,
              int* __restrict__ hist) {
    int t = blockIdx.x * 256 + threadIdx.x;
    if (t >= NPTS_TOT) return;
    const float* p = points + (size_t)t * 3;
    float x = __builtin_nontemporal_load(p + 0);
    float y = __builtin_nontemporal_load(p + 1);
    float z = __builtin_nontemporal_load(p + 2);
    // bit-identical to numpy ref: p / 2.2f + 0.5f ; clip[0, 1-1e-6] ; *64 ; floor
    const float LIM = 1.0f - 1e-6f;
    float cx = fminf(fmaxf(x / 2.2f + 0.5f, 0.0f), LIM);
    float cy = fminf(fmaxf(y / 2.2f + 0.5f, 0.0f), LIM);
    float cz = fminf(fmaxf(z / 2.2f + 0.5f, 0.0f), LIM);
    int i = (int)floorf(cx * 64.0f);
    int j = (int)floorf(cy * 64.0f);
    int k = (int)floorf(cz * 64.0f);
    int idx = i + RESO * (j + RESO * k);
    idxArr[t] = idx;
    int b = t / NPTS;
    atomicAdd(hist + b * R3 + idx, 1);
}

// ---------------- S1: per-chunk (1024 bins) exclusive scan ----------------
__global__ void __launch_bounds__(256)
s1_local_scan(const int* __restrict__ hist, int* __restrict__ lscan,
              int* __restrict__ ctot) {
    int chunk = blockIdx.x;            // 0..2047
    int tid = threadIdx.x;
    int4 v = *reinterpret_cast<const int4*>(hist + chunk * CHUNK + tid * 4);
    int tot = v.x + v.y + v.z + v.w;
    __shared__ int sm[256];
    sm[tid] = tot;
    __syncthreads();
    for (int off = 1; off < 256; off <<= 1) {
        int x = (tid >= off) ? sm[tid - off] : 0;
        __syncthreads();
        sm[tid] += x;
        __syncthreads();
    }
    int base = sm[tid] - tot;
    int4 o;
    o.x = base;
    o.y = base + v.x;
    o.z = base + v.x + v.y;
    o.w = base + v.x + v.y + v.z;
    *reinterpret_cast<int4*>(lscan + chunk * CHUNK + tid * 4) = o;
    if (tid == 255) ctot[chunk] = sm[255];
}

// ---------------- S2: single-block GLOBAL scan of 2048 chunk totals ----------------
__global__ void __launch_bounds__(256)
s2_chunk_scan(const int* __restrict__ ctot, int* __restrict__ coff) {
    int tid = threadIdx.x;
    int v[8];
#pragma unroll
    for (int j = 0; j < 8; ++j) v[j] = ctot[tid * 8 + j];
    int run = 0;
#pragma unroll
    for (int j = 0; j < 8; ++j) { int x = v[j]; v[j] = run; run += x; }
    __shared__ int sm[256];
    sm[tid] = run;
    __syncthreads();
    for (int off = 1; off < 256; off <<= 1) {
        int x = (tid >= off) ? sm[tid - off] : 0;
        __syncthreads();
        sm[tid] += x;
        __syncthreads();
    }
    int base = sm[tid] - run;
#pragma unroll
    for (int j = 0; j < 8; ++j) coff[tid * 8 + j] = base + v[j];
}

// ---- T (path A): transpose feature tile, convert fp16, scatter 64B rows to sorted order
__global__ void __launch_bounds__(256)
t_permute(const float* __restrict__ feature, const int* __restrict__ idxArr,
          int* __restrict__ lscan, const int* __restrict__ coff,
          ushort* __restrict__ fperm) {
    int b = blockIdx.y;
    int n0 = blockIdx.x * 256;
    int tid = threadIdx.x;
    int n = n0 + tid;
    bool valid = n < NPTS;

    __shared__ float sm[32][257];
    __shared__ int sm_pos[256];

    // phase 1: coalesced (nontemporal) load of 32x256 tile
    const float* fb = feature + (size_t)b * C_DIM * NPTS;
#pragma unroll
    for (int c = 0; c < C_DIM; ++c)
        sm[c][tid] = valid ? __builtin_nontemporal_load(fb + (size_t)c * NPTS + n) : 0.0f;

    // phase 1.5: sorted position per point (consumes the scan cursor)
    if (valid) {
        int idx = idxArr[b * NPTS + n];
        int g = b * R3 + idx;
        sm_pos[tid] = coff[g >> 10] + atomicAdd(lscan + g, 1);
    }
    __syncthreads();

    // phase 2: 4 lanes per point; each converts 8 channels to fp16, writes 16B
    // (normal stores: fperm should stay LLC-resident for k5)
    int cg = tid & 3;          // which 8-channel group
    int qb = tid >> 2;         // 0..63
#pragma unroll
    for (int it = 0; it < 4; ++it) {
        int q = it * 64 + qb;
        if (n0 + q < NPTS) {
            H8 r;
#pragma unroll
            for (int j = 0; j < 8; ++j)
                r.h[j] = (_Float16)sm[cg * 8 + j][q];
            *reinterpret_cast<uint4*>(fperm + (size_t)sm_pos[q] * C_DIM + cg * 8) = r.v;
        }
    }
}

// ---------------- K5 (path A): block-cooperative LDS-staged reduce + mean ----------------
__global__ void __launch_bounds__(256)
k5_reduce_a(const int* __restrict__ lscan, const int* __restrict__ coff,
            const int* __restrict__ hist, const ushort* __restrict__ fperm,
            float* __restrict__ out) {
    __shared__ uint4 srows[K5_LDS_ROWS * 4];   // 40 KB
    __shared__ int sb[2];

    int tid = threadIdx.x;
    int t = blockIdx.x * 256 + tid;            // global bin id
    int b = t >> 18;
    int v = t & (R3 - 1);
    int end = coff[t >> 10] + lscan[t];        // lscan = local_start + cnt now
    int cnt = hist[t];
    int start = end - cnt;

    // block's contiguous sorted-row range [rstart, rend)
    if (tid == 0) {
        int t0 = blockIdx.x * 256;
        sb[0] = (coff[t0 >> 10] + lscan[t0]) - hist[t0];
    }
    if (tid == 255) sb[1] = end;
    __syncthreads();
    int rstart = sb[0];
    int nrows = sb[1] - rstart;

    float acc[C_DIM];
#pragma unroll
    for (int c = 0; c < C_DIM; ++c) acc[c] = 0.0f;

    if (nrows <= K5_LDS_ROWS) {
        // cooperative, fully-coalesced staging of the block's rows
        const uint4* src = reinterpret_cast<const uint4*>(fperm + (size_t)rstart * C_DIM);
        int nvec = nrows * 4;
        for (int i = tid; i < nvec; i += 256)
            srows[i] = src[i];
        __syncthreads();
        for (int p = start; p < end; ++p) {
            const uint4* row = srows + (size_t)(p - rstart) * 4;
#pragma unroll
            for (int g = 0; g < 4; ++g) {
                H8 r;
                r.v = row[g];
#pragma unroll
                for (int j = 0; j < 8; ++j) acc[g * 8 + j] += (float)r.h[j];
            }
        }
    } else {
        // rare dense block: direct global reads (uniform branch per block)
        for (int p = start; p < end; ++p) {
            const uint4* row = reinterpret_cast<const uint4*>(fperm + (size_t)p * C_DIM);
#pragma unroll
            for (int g = 0; g < 4; ++g) {
                H8 r;
                r.v = row[g];
#pragma unroll
                for (int j = 0; j < 8; ++j) acc[g * 8 + j] += (float)r.h[j];
            }
        }
    }

    float d = (float)max(cnt, 1);
    size_t obase = ((size_t)b * C_DIM) * R3 + v;
#pragma unroll
    for (int c = 0; c < C_DIM; ++c)
        __builtin_nontemporal_store(acc[c] / d, out + obase + (size_t)c * R3);
}

// ---------------- Path B fallback (small workspace): round-2 pipeline ----------------
__global__ void __launch_bounds__(256)
k3_permute(const int* __restrict__ idxArr, int* __restrict__ lscan,
           const int* __restrict__ coff, int* __restrict__ perm) {
    int t = blockIdx.x * 256 + threadIdx.x;
    if (t >= NPTS_TOT) return;
    int b = t / NPTS;
    int g = b * R3 + idxArr[t];
    int pos = coff[g >> 10] + atomicAdd(lscan + g, 1);
    perm[pos] = t;
}

__global__ void __launch_bounds__(256)
k5_reduce_b(const int* __restrict__ lscan, const int* __restrict__ coff,
            const int* __restrict__ hist, const int* __restrict__ perm,
            const float* __restrict__ feature, float* __restrict__ out) {
    int t = blockIdx.x * 256 + threadIdx.x;
    int b = t >> 18;
    int v = t & (R3 - 1);
    int end = coff[t >> 10] + lscan[t];
    int cnt = hist[t];
    int start = end - cnt;

    float acc[C_DIM];
#pragma unroll
    for (int c = 0; c < C_DIM; ++c) acc[c] = 0.0f;
    const float* fb = feature + (size_t)b * C_DIM * NPTS;
    for (int p = start; p < end; ++p) {
        int n = perm[p] - b * NPTS;
#pragma unroll
        for (int c = 0; c < C_DIM; ++c) acc[c] += fb[(size_t)c * NPTS + n];
    }
    float d = (float)max(cnt, 1);
    size_t obase = ((size_t)b * C_DIM) * R3 + v;
#pragma unroll
    for (int c = 0; c < C_DIM; ++c) out[obase + (size_t)c * R3] = acc[c] / d;
}

extern "C" void kernel_launch(void* const* d_in, const int* in_sizes, int n_in,
                              void* d_out, int out_size, void* d_ws, size_t ws_size,
                              hipStream_t stream) {
    const float* points  = (const float*)d_in[0];   // [B, N, 3]
    const float* feature = (const float*)d_in[1];   // [B, C, N]
    float* out = (float*)d_out;                     // [B, C, R3]

    char* ws = (char*)d_ws;
    int* idxArr = (int*)(ws + OFF_IDX);
    int* hist   = (int*)(ws + OFF_HIST);
    int* lscan  = (int*)(ws + OFF_LSCAN);
    int* ctot   = (int*)(ws + OFF_CTOT);
    int* coff   = (int*)(ws + OFF_COFF);

    hipMemsetAsync(hist, 0, (size_t)NB * R3 * sizeof(int), stream);

    k1_index_hist<<<(NPTS_TOT + 255) / 256, 256, 0, stream>>>(points, idxArr, hist);
    s1_local_scan<<<TOTCHUNK, 256, 0, stream>>>(hist, lscan, ctot);
    s2_chunk_scan<<<1, 256, 0, stream>>>(ctot, coff);

    if (ws_size >= WS_NEED_A) {
        ushort* fperm = (ushort*)(ws + OFF_FPERM);
        dim3 tgrid(NTILE, NB);
        t_permute<<<tgrid, 256, 0, stream>>>(feature, idxArr, lscan, coff, fperm);
        k5_reduce_a<<<(NB * R3) / 256, 256, 0, stream>>>(lscan, coff, hist, fperm, out);
    } else {
        int* perm = (int*)(ws + OFF_PERM);
        k3_permute<<<(NPTS_TOT + 255) / 256, 256, 0, stream>>>(idxArr, lscan, coff, perm);
        k5_reduce_b<<<(NB * R3) / 256, 256, 0, stream>>>(lscan, coff, hist, perm, feature, out);
    }
}

// Round 7
// 443.923 us; speedup vs baseline: 1.0075x; 1.0075x over previous
//
#include <hip/hip_runtime.h>

#define NB 8
#define NPTS 100000
#define C_DIM 32
#define RESO 64
#define R3 (RESO * RESO * RESO)     // 262144 = 2^18
#define CHUNK 1024                  // bins per scan chunk
#define NCHUNK (R3 / CHUNK)         // 256 chunks per batch
#define TOTCHUNK (NB * NCHUNK)      // 2048 chunks total
#define NPTS_TOT (NB * NPTS)        // 800000
#define NTILE ((NPTS + 255) / 256)  // 391 tiles per batch

// Workspace layout (byte offsets, 16B-aligned)
#define OFF_IDX   0u                              // [800000] int
#define OFF_HIST  3200000u                        // [B*R3] int (8 MB)
#define OFF_LSCAN (OFF_HIST + 8388608u)           // [B*R3] int (8 MB)
#define OFF_CTOT  (OFF_LSCAN + 8388608u)          // [2048] int
#define OFF_COFF  (OFF_CTOT + 8192u)              // [2048] int
#define OFF_PERM  (OFF_COFF + 8192u)              // path B: [800000] int
#define OFF_FPERM (OFF_COFF + 8192u)              // path A: [800000][32] fp16 (51.2 MB)
#define WS_NEED_A (OFF_FPERM + (size_t)NPTS_TOT * C_DIM * 2)
#define WS_NEED_B (OFF_PERM + (size_t)NPTS_TOT * 4)

union H8 { uint4 v; _Float16 h[8]; };
typedef float vf4 __attribute__((ext_vector_type(4)));

// ---------------- K1: bin index per point + histogram ----------------
__global__ void __launch_bounds__(256)
k1_index_hist(const float* __restrict__ points, int* __restrict__ idxArr,
              int* __restrict__ hist) {
    int t = blockIdx.x * 256 + threadIdx.x;
    if (t >= NPTS_TOT) return;
    const float* p = points + (size_t)t * 3;
    float x = __builtin_nontemporal_load(p + 0);
    float y = __builtin_nontemporal_load(p + 1);
    float z = __builtin_nontemporal_load(p + 2);
    // bit-identical to numpy ref: p / 2.2f + 0.5f ; clip[0, 1-1e-6] ; *64 ; floor
    const float LIM = 1.0f - 1e-6f;
    float cx = fminf(fmaxf(x / 2.2f + 0.5f, 0.0f), LIM);
    float cy = fminf(fmaxf(y / 2.2f + 0.5f, 0.0f), LIM);
    float cz = fminf(fmaxf(z / 2.2f + 0.5f, 0.0f), LIM);
    int i = (int)floorf(cx * 64.0f);
    int j = (int)floorf(cy * 64.0f);
    int k = (int)floorf(cz * 64.0f);
    int idx = i + RESO * (j + RESO * k);
    idxArr[t] = idx;
    int b = t / NPTS;
    atomicAdd(hist + b * R3 + idx, 1);
}

// ---------------- S1: per-chunk (1024 bins) exclusive scan ----------------
__global__ void __launch_bounds__(256)
s1_local_scan(const int* __restrict__ hist, int* __restrict__ lscan,
              int* __restrict__ ctot) {
    int chunk = blockIdx.x;            // 0..2047
    int tid = threadIdx.x;
    int4 v = *reinterpret_cast<const int4*>(hist + chunk * CHUNK + tid * 4);
    int tot = v.x + v.y + v.z + v.w;
    __shared__ int sm[256];
    sm[tid] = tot;
    __syncthreads();
    for (int off = 1; off < 256; off <<= 1) {
        int x = (tid >= off) ? sm[tid - off] : 0;
        __syncthreads();
        sm[tid] += x;
        __syncthreads();
    }
    int base = sm[tid] - tot;
    int4 o;
    o.x = base;
    o.y = base + v.x;
    o.z = base + v.x + v.y;
    o.w = base + v.x + v.y + v.z;
    *reinterpret_cast<int4*>(lscan + chunk * CHUNK + tid * 4) = o;
    if (tid == 255) ctot[chunk] = sm[255];
}

// ---------------- S2: single-block GLOBAL scan of 2048 chunk totals ----------------
__global__ void __launch_bounds__(256)
s2_chunk_scan(const int* __restrict__ ctot, int* __restrict__ coff) {
    int tid = threadIdx.x;
    int v[8];
#pragma unroll
    for (int j = 0; j < 8; ++j) v[j] = ctot[tid * 8 + j];
    int run = 0;
#pragma unroll
    for (int j = 0; j < 8; ++j) { int x = v[j]; v[j] = run; run += x; }
    __shared__ int sm[256];
    sm[tid] = run;
    __syncthreads();
    for (int off = 1; off < 256; off <<= 1) {
        int x = (tid >= off) ? sm[tid - off] : 0;
        __syncthreads();
        sm[tid] += x;
        __syncthreads();
    }
    int base = sm[tid] - run;
#pragma unroll
    for (int j = 0; j < 8; ++j) coff[tid * 8 + j] = base + v[j];
}

// ---- T (path A): transpose feature tile, convert fp16, scatter 64B rows to sorted order
__global__ void __launch_bounds__(256)
t_permute(const float* __restrict__ feature, const int* __restrict__ idxArr,
          int* __restrict__ lscan, const int* __restrict__ coff,
          ushort* __restrict__ fperm) {
    int b = blockIdx.y;
    int n0 = blockIdx.x * 256;
    int tid = threadIdx.x;
    int n = n0 + tid;
    bool valid = n < NPTS;

    __shared__ float sm[32][257];
    __shared__ int sm_pos[256];

    // phase 1: coalesced (nontemporal) load of 32x256 tile
    const float* fb = feature + (size_t)b * C_DIM * NPTS;
#pragma unroll
    for (int c = 0; c < C_DIM; ++c)
        sm[c][tid] = valid ? __builtin_nontemporal_load(fb + (size_t)c * NPTS + n) : 0.0f;

    // phase 1.5: sorted position per point (consumes the scan cursor)
    if (valid) {
        int idx = idxArr[b * NPTS + n];
        int g = b * R3 + idx;
        sm_pos[tid] = coff[g >> 10] + atomicAdd(lscan + g, 1);
    }
    __syncthreads();

    // phase 2: 4 lanes per point; each converts 8 channels to fp16, writes 16B
    int cg = tid & 3;          // which 8-channel group
    int qb = tid >> 2;         // 0..63
#pragma unroll
    for (int it = 0; it < 4; ++it) {
        int q = it * 64 + qb;
        if (n0 + q < NPTS) {
            H8 r;
#pragma unroll
            for (int j = 0; j < 8; ++j)
                r.h[j] = (_Float16)sm[cg * 8 + j][q];
            *reinterpret_cast<uint4*>(fperm + (size_t)sm_pos[q] * C_DIM + cg * 8) = r.v;
        }
    }
}

// ---- K5 (path A): per-voxel reduce + mean, LDS-transposed 16B NT stores ----
__global__ void __launch_bounds__(256)
k5_reduce_a(const int* __restrict__ lscan, const int* __restrict__ coff,
            const int* __restrict__ hist, const ushort* __restrict__ fperm,
            float* __restrict__ out) {
    __shared__ float sm[16][256];              // 16 KB: half the channels at a time

    int tid = threadIdx.x;
    int t = blockIdx.x * 256 + tid;            // global bin id
    int b = t >> 18;
    int v0 = (blockIdx.x * 256) & (R3 - 1);    // first voxel of block
    int end = coff[t >> 10] + lscan[t];        // lscan = local_start + cnt now
    int cnt = hist[t];
    int start = end - cnt;

    float acc[C_DIM];
#pragma unroll
    for (int c = 0; c < C_DIM; ++c) acc[c] = 0.0f;

    for (int p = start; p < end; ++p) {
        const uint4* row = reinterpret_cast<const uint4*>(fperm + (size_t)p * C_DIM);
#pragma unroll
        for (int g = 0; g < 4; ++g) {
            H8 r;
            r.v = row[g];
#pragma unroll
            for (int j = 0; j < 8; ++j) acc[g * 8 + j] += (float)r.h[j];
        }
    }
    float d = (float)max(cnt, 1);
#pragma unroll
    for (int c = 0; c < C_DIM; ++c) acc[c] /= d;

    // two halves: stage 16 channels x 256 bins in LDS, store as 16B NT rows
    float* obase = out + ((size_t)b * C_DIM) * R3 + v0;
#pragma unroll
    for (int h = 0; h < 2; ++h) {
        __syncthreads();
#pragma unroll
        for (int c = 0; c < 16; ++c) sm[c][tid] = acc[h * 16 + c];
        __syncthreads();
        // flat = u*256 + tid ; c = flat>>6 ; q = flat&63  (wave-contiguous 1KB rows)
#pragma unroll
        for (int u = 0; u < 4; ++u) {
            int flat = u * 256 + tid;
            int c = flat >> 6;                 // 0..15
            int q = flat & 63;                 // float4 index in channel row
            vf4 val = *reinterpret_cast<const vf4*>(&sm[c][q * 4]);
            vf4* dst = reinterpret_cast<vf4*>(obase + (size_t)(h * 16 + c) * R3 + q * 4);
            __builtin_nontemporal_store(val, dst);
        }
    }
}

// ---------------- Path B fallback (small workspace): round-2 pipeline ----------------
__global__ void __launch_bounds__(256)
k3_permute(const int* __restrict__ idxArr, int* __restrict__ lscan,
           const int* __restrict__ coff, int* __restrict__ perm) {
    int t = blockIdx.x * 256 + threadIdx.x;
    if (t >= NPTS_TOT) return;
    int b = t / NPTS;
    int g = b * R3 + idxArr[t];
    int pos = coff[g >> 10] + atomicAdd(lscan + g, 1);
    perm[pos] = t;
}

__global__ void __launch_bounds__(256)
k5_reduce_b(const int* __restrict__ lscan, const int* __restrict__ coff,
            const int* __restrict__ hist, const int* __restrict__ perm,
            const float* __restrict__ feature, float* __restrict__ out) {
    int t = blockIdx.x * 256 + threadIdx.x;
    int b = t >> 18;
    int v = t & (R3 - 1);
    int end = coff[t >> 10] + lscan[t];
    int cnt = hist[t];
    int start = end - cnt;

    float acc[C_DIM];
#pragma unroll
    for (int c = 0; c < C_DIM; ++c) acc[c] = 0.0f;
    const float* fb = feature + (size_t)b * C_DIM * NPTS;
    for (int p = start; p < end; ++p) {
        int n = perm[p] - b * NPTS;
#pragma unroll
        for (int c = 0; c < C_DIM; ++c) acc[c] += fb[(size_t)c * NPTS + n];
    }
    float d = (float)max(cnt, 1);
    size_t obase = ((size_t)b * C_DIM) * R3 + v;
#pragma unroll
    for (int c = 0; c < C_DIM; ++c) out[obase + (size_t)c * R3] = acc[c] / d;
}

extern "C" void kernel_launch(void* const* d_in, const int* in_sizes, int n_in,
                              void* d_out, int out_size, void* d_ws, size_t ws_size,
                              hipStream_t stream) {
    const float* points  = (const float*)d_in[0];   // [B, N, 3]
    const float* feature = (const float*)d_in[1];   // [B, C, N]
    float* out = (float*)d_out;                     // [B, C, R3]

    char* ws = (char*)d_ws;
    int* idxArr = (int*)(ws + OFF_IDX);
    int* hist   = (int*)(ws + OFF_HIST);
    int* lscan  = (int*)(ws + OFF_LSCAN);
    int* ctot   = (int*)(ws + OFF_CTOT);
    int* coff   = (int*)(ws + OFF_COFF);

    (void)hipMemsetAsync(hist, 0, (size_t)NB * R3 * sizeof(int), stream);

    k1_index_hist<<<(NPTS_TOT + 255) / 256, 256, 0, stream>>>(points, idxArr, hist);
    s1_local_scan<<<TOTCHUNK, 256, 0, stream>>>(hist, lscan, ctot);
    s2_chunk_scan<<<1, 256, 0, stream>>>(ctot, coff);

    if (ws_size >= WS_NEED_A) {
        ushort* fperm = (ushort*)(ws + OFF_FPERM);
        dim3 tgrid(NTILE, NB);
        t_permute<<<tgrid, 256, 0, stream>>>(feature, idxArr, lscan, coff, fperm);
        k5_reduce_a<<<(NB * R3) / 256, 256, 0, stream>>>(lscan, coff, hist, fperm, out);
    } else {
        int* perm = (int*)(ws + OFF_PERM);
        k3_permute<<<(NPTS_TOT + 255) / 256, 256, 0, stream>>>(idxArr, lscan, coff, perm);
        k5_reduce_b<<<(NB * R3) / 256, 256, 0, stream>>>(lscan, coff, hist, perm, feature, out);
    }
}